// Round 1
// baseline (112.790 us; speedup 1.0000x reference)
//
#include <hip/hip_runtime.h>
#include <hip/hip_bf16.h>
#include <stdint.h>

typedef __attribute__((ext_vector_type(8))) short short8;
typedef __attribute__((ext_vector_type(4))) float f32x4;

__device__ inline unsigned short f2bf(float f) {
  union { float f; unsigned u; } v; v.f = f;
  unsigned r = v.u + 0x7fffu + ((v.u >> 16) & 1u);
  return (unsigned short)(r >> 16);
}

// -------- kernel 1: reconstruct T (1024x1024) as bf16, layout [m][n] (n=K contiguous) ----
// T[m,n] = sum_{r1,r2,r3} c0[m0*8+r1, n0] c1[m1*8+r2, r1*8+n1] c2[m2*8+r3, r2*8+n2] c3[m3, r3*4+n3]
// via L[m0,m1,r2,n0,n1] = sum_r1 c0*c1  and  R[r2,m2,m3,n2,n3] = sum_r3 c2*c3
__global__ __launch_bounds__(256) void tt_build_T(
    const float* __restrict__ c0, const float* __restrict__ c1,
    const float* __restrict__ c2, const float* __restrict__ c3,
    unsigned short* __restrict__ Tb) {
  __shared__ float L[8192];
  __shared__ float R[8192];
  int t = threadIdx.x;
  for (int i = t; i < 8192; i += 256) {
    int n1 = i & 7, n0 = (i >> 3) & 3, r2 = (i >> 5) & 7, m1 = (i >> 8) & 7, m0 = i >> 11;
    float s = 0.f;
#pragma unroll
    for (int r1 = 0; r1 < 8; ++r1)
      s += c0[(m0 * 8 + r1) * 4 + n0] * c1[(m1 * 8 + r2) * 64 + r1 * 8 + n1];
    L[i] = s;
  }
  for (int i = t; i < 8192; i += 256) {
    int n3 = i & 3, n2 = (i >> 2) & 7, m3 = (i >> 5) & 3, m2 = (i >> 7) & 7, r2 = i >> 10;
    float s = 0.f;
#pragma unroll
    for (int r3 = 0; r3 < 8; ++r3)
      s += c2[(m2 * 8 + r3) * 64 + r2 * 8 + n2] * c3[m3 * 32 + r3 * 4 + n3];
    R[i] = s;
  }
  __syncthreads();
  int base = blockIdx.x * 16384;  // 16 rows of T per block, grid = 64
  for (int j = 0; j < 64; ++j) {
    int lin = j * 256 + t;  // 0..16383
    int g = base + lin;
    int m = g >> 10, n = g & 1023;
    int m0 = m >> 8, m1 = (m >> 5) & 7, m2 = (m >> 2) & 7, m3 = m & 3;
    int n0 = n >> 8, n1 = (n >> 5) & 7, n2 = (n >> 2) & 7, n3 = n & 3;
    float s = 0.f;
#pragma unroll
    for (int r2 = 0; r2 < 8; ++r2)
      s += L[(((m0 * 8 + m1) * 8 + r2) * 4 + n0) * 8 + n1] *
           R[(((r2 * 8 + m2) * 4 + m3) * 8 + n2) * 4 + n3];
    Tb[(size_t)m * 1024 + n] = f2bf(s);
  }
}

// -------- kernel 2: depthwise 3x3 SAME conv (single shared filter), fp32 -> bf16 --------
// D[p][c] with p = b*1024 + h*32 + w, c contiguous (GEMM A operand, K-contiguous)
__global__ __launch_bounds__(256) void tt_conv3x3(
    const float* __restrict__ x, const float* __restrict__ filt,
    unsigned short* __restrict__ D) {
  int p = blockIdx.x;  // 0 .. 16383
  int w = p & 31, h = (p >> 5) & 31;
  int c = threadIdx.x * 4;
  float F[9];
#pragma unroll
  for (int i = 0; i < 9; ++i) F[i] = filt[i];
  const float* xb = x + ((size_t)p << 10);
  float a0 = 0.f, a1 = 0.f, a2 = 0.f, a3 = 0.f;
#pragma unroll
  for (int dh = -1; dh <= 1; ++dh) {
    int hh = h + dh;
    if ((unsigned)hh >= 32u) continue;
#pragma unroll
    for (int dw = -1; dw <= 1; ++dw) {
      int ww = w + dw;
      if ((unsigned)ww >= 32u) continue;
      const float4 v = *reinterpret_cast<const float4*>(xb + (ptrdiff_t)(dh * 32 + dw) * 1024 + c);
      float fv = F[(dh + 1) * 3 + (dw + 1)];
      a0 += fv * v.x; a1 += fv * v.y; a2 += fv * v.z; a3 += fv * v.w;
    }
  }
  ushort4 o;
  o.x = f2bf(a0); o.y = f2bf(a1); o.z = f2bf(a2); o.w = f2bf(a3);
  *reinterpret_cast<ushort4*>(&D[((size_t)p << 10) + c]) = o;
}

// -------- kernel 3: GEMM  C[p,m] = relu( sum_k D[p,k]*Tb[m,k] + bias[m] ) --------
// m97 structure: 128x128 tile, BK=32, 4 waves (2x2), global_load_lds width 16.
#define BM 128
#define BK 32

__device__ inline void stage16(const void* g, void* l) {
  __builtin_amdgcn_global_load_lds(
      (const __attribute__((address_space(1))) void*)g,
      (__attribute__((address_space(3))) void*)l, 16, 0, 0);
}

__global__ __launch_bounds__(256) void tt_gemm_bt(
    const unsigned short* __restrict__ A,   // [M=16384, K=1024]
    const unsigned short* __restrict__ Bt,  // [N=1024,  K=1024]
    const float* __restrict__ bias,
    float* __restrict__ C) {
  const int M = 16384, N = 1024, K = 1024;
  __shared__ __align__(16) unsigned short As[BM * BK];
  __shared__ __align__(16) unsigned short Bs[BM * BK];
  int tid = threadIdx.x;
  int wave = tid >> 6, lane = tid & 63;
  int brow = blockIdx.x * BM;
  int bcol = blockIdx.y * BM;
  int wr = wave >> 1, wc = wave & 1;

  f32x4 acc[4][4] = {};

  // staging: each wave stages 32 rows (2 calls x 16 rows); lane l -> row l/4, k-chunk (l&3)*8
  int srow = lane >> 2;
  int skb = (lane & 3) * 8;
  int lr = lane & 15;
  int lk = (lane >> 4) * 8;

  for (int kt = 0; kt < K; kt += BK) {
#pragma unroll
    for (int j = 0; j < 2; ++j) {
      int r = wave * 32 + j * 16 + srow;
      stage16(&A[(size_t)(brow + r) * K + kt + skb], &As[r * BK + skb]);
      stage16(&Bt[(size_t)(bcol + r) * K + kt + skb], &Bs[r * BK + skb]);
    }
    __syncthreads();
    short8 af[4], bfr[4];
#pragma unroll
    for (int m = 0; m < 4; ++m)
      af[m] = *reinterpret_cast<const short8*>(&As[(wr * 64 + m * 16 + lr) * BK + lk]);
#pragma unroll
    for (int n = 0; n < 4; ++n)
      bfr[n] = *reinterpret_cast<const short8*>(&Bs[(wc * 64 + n * 16 + lr) * BK + lk]);
#pragma unroll
    for (int m = 0; m < 4; ++m)
#pragma unroll
      for (int n = 0; n < 4; ++n)
        acc[m][n] = __builtin_amdgcn_mfma_f32_16x16x32_bf16(af[m], bfr[n], acc[m][n], 0, 0, 0);
    __syncthreads();
  }

  int rg = lane >> 4;
#pragma unroll
  for (int m = 0; m < 4; ++m) {
#pragma unroll
    for (int n = 0; n < 4; ++n) {
      int col = bcol + wc * 64 + n * 16 + lr;
      float bv = bias[col];
#pragma unroll
      for (int j = 0; j < 4; ++j) {
        int row = brow + wr * 64 + m * 16 + rg * 4 + j;
        float v = acc[m][n][j] + bv;
        C[(size_t)row * N + col] = v > 0.f ? v : 0.f;
      }
    }
  }
}

extern "C" void kernel_launch(void* const* d_in, const int* in_sizes, int n_in,
                              void* d_out, int out_size, void* d_ws, size_t ws_size,
                              hipStream_t stream) {
  const float* x = (const float*)d_in[0];
  const float* filt = (const float*)d_in[1];
  const float* c0 = (const float*)d_in[2];
  const float* c1 = (const float*)d_in[3];
  const float* c2 = (const float*)d_in[4];
  const float* c3 = (const float*)d_in[5];
  const float* bias = (const float*)d_in[6];
  float* out = (float*)d_out;

  unsigned short* Tb = (unsigned short*)d_ws;               // 1024*1024 u16 = 2 MB
  unsigned short* D = Tb + (size_t)1024 * 1024;             // 16384*1024 u16 = 32 MB

  tt_build_T<<<64, 256, 0, stream>>>(c0, c1, c2, c3, Tb);
  tt_conv3x3<<<16384, 256, 0, stream>>>(x, filt, D);
  dim3 grid(16384 / BM, 1024 / BM);
  tt_gemm_bt<<<grid, 256, 0, stream>>>(D, Tb, bias, out);
}

// Round 2
// 101.859 us; speedup vs baseline: 1.1073x; 1.1073x over previous
//
#include <hip/hip_runtime.h>
#include <hip/hip_bf16.h>
#include <stdint.h>

typedef __attribute__((ext_vector_type(8))) short short8;
typedef __attribute__((ext_vector_type(4))) float f32x4;

__device__ inline unsigned short f2bf(float f) {
  union { float f; unsigned u; } v; v.f = f;
  unsigned r = v.u + 0x7fffu + ((v.u >> 16) & 1u);
  return (unsigned short)(r >> 16);
}

// -------- kernel 1: reconstruct T (1024x1024) as bf16, layout [m][n] (n=K contiguous) ----
__global__ __launch_bounds__(256) void tt_build_T(
    const float* __restrict__ c0, const float* __restrict__ c1,
    const float* __restrict__ c2, const float* __restrict__ c3,
    unsigned short* __restrict__ Tb) {
  __shared__ float L[8192];
  __shared__ float R[8192];
  int t = threadIdx.x;
  for (int i = t; i < 8192; i += 256) {
    int n1 = i & 7, n0 = (i >> 3) & 3, r2 = (i >> 5) & 7, m1 = (i >> 8) & 7, m0 = i >> 11;
    float s = 0.f;
#pragma unroll
    for (int r1 = 0; r1 < 8; ++r1)
      s += c0[(m0 * 8 + r1) * 4 + n0] * c1[(m1 * 8 + r2) * 64 + r1 * 8 + n1];
    L[i] = s;
  }
  for (int i = t; i < 8192; i += 256) {
    int n3 = i & 3, n2 = (i >> 2) & 7, m3 = (i >> 5) & 3, m2 = (i >> 7) & 7, r2 = i >> 10;
    float s = 0.f;
#pragma unroll
    for (int r3 = 0; r3 < 8; ++r3)
      s += c2[(m2 * 8 + r3) * 64 + r2 * 8 + n2] * c3[m3 * 32 + r3 * 4 + n3];
    R[i] = s;
  }
  __syncthreads();
  int base = blockIdx.x * 16384;
  for (int j = 0; j < 64; ++j) {
    int lin = j * 256 + t;
    int g = base + lin;
    int m = g >> 10, n = g & 1023;
    int m0 = m >> 8, m1 = (m >> 5) & 7, m2 = (m >> 2) & 7, m3 = m & 3;
    int n0 = n >> 8, n1 = (n >> 5) & 7, n2 = (n >> 2) & 7, n3 = n & 3;
    float s = 0.f;
#pragma unroll
    for (int r2 = 0; r2 < 8; ++r2)
      s += L[(((m0 * 8 + m1) * 8 + r2) * 4 + n0) * 8 + n1] *
           R[(((r2 * 8 + m2) * 4 + m3) * 8 + n2) * 4 + n3];
    Tb[(size_t)m * 1024 + n] = f2bf(s);
  }
}

// -------- kernel 2: depthwise 3x3 SAME conv (single shared filter), fp32 -> bf16 --------
__global__ __launch_bounds__(256) void tt_conv3x3(
    const float* __restrict__ x, const float* __restrict__ filt,
    unsigned short* __restrict__ D) {
  int p = blockIdx.x;
  int w = p & 31, h = (p >> 5) & 31;
  int c = threadIdx.x * 4;
  float F[9];
#pragma unroll
  for (int i = 0; i < 9; ++i) F[i] = filt[i];
  const float* xb = x + ((size_t)p << 10);
  float a0 = 0.f, a1 = 0.f, a2 = 0.f, a3 = 0.f;
#pragma unroll
  for (int dh = -1; dh <= 1; ++dh) {
    int hh = h + dh;
    if ((unsigned)hh >= 32u) continue;
#pragma unroll
    for (int dw = -1; dw <= 1; ++dw) {
      int ww = w + dw;
      if ((unsigned)ww >= 32u) continue;
      const float4 v = *reinterpret_cast<const float4*>(xb + (ptrdiff_t)(dh * 32 + dw) * 1024 + c);
      float fv = F[(dh + 1) * 3 + (dw + 1)];
      a0 += fv * v.x; a1 += fv * v.y; a2 += fv * v.z; a3 += fv * v.w;
    }
  }
  ushort4 o;
  o.x = f2bf(a0); o.y = f2bf(a1); o.z = f2bf(a2); o.w = f2bf(a3);
  *reinterpret_cast<ushort4*>(&D[((size_t)p << 10) + c]) = o;
}

// -------- kernel 3: deep-pipelined 256x256 GEMM, BK=32, 4-slot LDS ring, counted vmcnt --
// C[p,m] = relu( sum_k D[p,k]*Tb[m,k] + bias[m] ), M=16384, N=1024, K=1024.
// LDS swizzle: rows paired into 128B lines; 16B chunk j' = j ^ (line&7).
// Staging pre-swizzles the GLOBAL source address; LDS dest stays linear (gload_lds rule).

__device__ inline void stage16(const unsigned short* g, unsigned short* l) {
  __builtin_amdgcn_global_load_lds(
      (const __attribute__((address_space(1))) void*)g,
      (__attribute__((address_space(3))) void*)l, 16, 0, 0);
}

#define GNT 32  // K / 32

__global__ __launch_bounds__(512, 2) void tt_gemm_ring(
    const unsigned short* __restrict__ A,   // [16384, 1024] bf16 (conv out)
    const unsigned short* __restrict__ Bt,  // [1024, 1024] bf16 (T)
    const float* __restrict__ bias,
    float* __restrict__ C) {
  __shared__ unsigned short lds[4][2][8192];  // [ring][A/B][256rows x 32k], 128 KiB
  const int tid = threadIdx.x;
  const int lane = tid & 63, wave = tid >> 6;
  const int wr = wave >> 2, wc = wave & 3;          // 2 x 4 waves
  const int lr = lane & 15, kc = lane >> 4;

  // XCD-bijective block swizzle: 256 blocks, 8 XCDs, 32 contiguous logical tiles/XCD
  int lin = blockIdx.x + blockIdx.y * 64;           // grid (64, 4)
  int Lg = ((lin & 7) << 5) | (lin >> 3);
  int brow = (Lg & 63) * 256;
  int bcol = (Lg >> 6) * 256;

  // staging descriptors: thread stages chunks q0,q1 of each operand tile
  const int q0 = tid, q1 = tid + 512;
  int ra0, ka0, ra1, ka1;
  { int lam = q0 >> 3, jp = q0 & 7, j = jp ^ (lam & 7); ra0 = 2 * lam + (j >> 2); ka0 = j & 3; }
  { int lam = q1 >> 3, jp = q1 & 7, j = jp ^ (lam & 7); ra1 = 2 * lam + (j >> 2); ka1 = j & 3; }
  const unsigned short* pa0 = A + (size_t)(brow + ra0) * 1024 + ka0 * 8;
  const unsigned short* pa1 = A + (size_t)(brow + ra1) * 1024 + ka1 * 8;
  const unsigned short* pb0 = Bt + (size_t)(bcol + ra0) * 1024 + ka0 * 8;
  const unsigned short* pb1 = Bt + (size_t)(bcol + ra1) * 1024 + ka1 * 8;

  // ds_read fragment offsets (shorts), swizzled
  int offA[8], offB[4];
#pragma unroll
  for (int m = 0; m < 8; ++m) {
    int row = wr * 128 + m * 16 + lr;
    int lam = row >> 1, jp = ((row & 1) * 4 + kc) ^ (lam & 7);
    offA[m] = lam * 64 + jp * 8;
  }
#pragma unroll
  for (int n = 0; n < 4; ++n) {
    int row = wc * 64 + n * 16 + lr;
    int lam = row >> 1, jp = ((row & 1) * 4 + kc) ^ (lam & 7);
    offB[n] = lam * 64 + jp * 8;
  }

  f32x4 acc[8][4] = {};

#define STAGE(u) { \
    unsigned short* La = &lds[(u) & 3][0][0]; \
    unsigned short* Lb = &lds[(u) & 3][1][0]; \
    stage16(pa0 + (u) * 32, La + q0 * 8); \
    stage16(pa1 + (u) * 32, La + q1 * 8); \
    stage16(pb0 + (u) * 32, Lb + q0 * 8); \
    stage16(pb1 + (u) * 32, Lb + q1 * 8); }

#define COMPUTE(t) { \
    const unsigned short* Ab = &lds[(t) & 3][0][0]; \
    const unsigned short* Bb = &lds[(t) & 3][1][0]; \
    short8 af[8], bf[4]; \
    _Pragma("unroll") for (int m = 0; m < 8; ++m) \
      af[m] = *reinterpret_cast<const short8*>(Ab + offA[m]); \
    _Pragma("unroll") for (int n = 0; n < 4; ++n) \
      bf[n] = *reinterpret_cast<const short8*>(Bb + offB[n]); \
    __builtin_amdgcn_s_setprio(1); \
    _Pragma("unroll") for (int m = 0; m < 8; ++m) \
      _Pragma("unroll") for (int n = 0; n < 4; ++n) \
        acc[m][n] = __builtin_amdgcn_mfma_f32_16x16x32_bf16(af[m], bf[n], acc[m][n], 0, 0, 0); \
    __builtin_amdgcn_s_setprio(0); }

#define ITER(t, VM, DO_STAGE) { \
    asm volatile("s_waitcnt vmcnt(" #VM ")" ::: "memory"); \
    __builtin_amdgcn_s_barrier(); \
    asm volatile("" ::: "memory"); \
    if (DO_STAGE) STAGE((t) + 3); \
    COMPUTE(t); }

  // prologue: tiles 0..2 in flight (12 loads)
  STAGE(0); STAGE(1); STAGE(2);

  for (int t = 0; t < GNT - 3; ++t) ITER(t, 8, 1);
  ITER(GNT - 3, 8, 0);
  ITER(GNT - 2, 4, 0);
  ITER(GNT - 1, 0, 0);

#undef ITER
#undef COMPUTE
#undef STAGE

  // epilogue: bias + relu, fp32 store
#pragma unroll
  for (int n = 0; n < 4; ++n) {
    int col = bcol + wc * 64 + n * 16 + lr;
    float bv = bias[col];
#pragma unroll
    for (int m = 0; m < 8; ++m) {
#pragma unroll
      for (int j = 0; j < 4; ++j) {
        int row = brow + wr * 128 + m * 16 + kc * 4 + j;
        float v = acc[m][n][j] + bv;
        C[(size_t)row * 1024 + col] = v > 0.f ? v : 0.f;
      }
    }
  }
}

extern "C" void kernel_launch(void* const* d_in, const int* in_sizes, int n_in,
                              void* d_out, int out_size, void* d_ws, size_t ws_size,
                              hipStream_t stream) {
  const float* x = (const float*)d_in[0];
  const float* filt = (const float*)d_in[1];
  const float* c0 = (const float*)d_in[2];
  const float* c1 = (const float*)d_in[3];
  const float* c2 = (const float*)d_in[4];
  const float* c3 = (const float*)d_in[5];
  const float* bias = (const float*)d_in[6];
  float* out = (float*)d_out;

  unsigned short* Tb = (unsigned short*)d_ws;        // 2 MB
  unsigned short* D = Tb + (size_t)1024 * 1024;      // 32 MB

  tt_build_T<<<64, 256, 0, stream>>>(c0, c1, c2, c3, Tb);
  tt_conv3x3<<<16384, 256, 0, stream>>>(x, filt, D);
  dim3 grid(64, 4);
  tt_gemm_ring<<<grid, 512, 0, stream>>>(D, Tb, bias, out);
}

// Round 3
// 82.417 us; speedup vs baseline: 1.3685x; 1.2359x over previous
//
#include <hip/hip_runtime.h>
#include <hip/hip_bf16.h>
#include <stdint.h>

typedef __attribute__((ext_vector_type(8))) short short8;
typedef __attribute__((ext_vector_type(4))) float f32x4;

__device__ inline unsigned short f2bf(float f) {
  union { float f; unsigned u; } v; v.f = f;
  unsigned r = v.u + 0x7fffu + ((v.u >> 16) & 1u);
  return (unsigned short)(r >> 16);
}

// -------- kernel 1: reconstruct T (1024x1024) as bf16, layout [m][n] ----
__global__ __launch_bounds__(256) void tt_build_T(
    const float* __restrict__ c0, const float* __restrict__ c1,
    const float* __restrict__ c2, const float* __restrict__ c3,
    unsigned short* __restrict__ Tb) {
  __shared__ float L[8192];
  __shared__ float R[8192];
  int t = threadIdx.x;
  for (int i = t; i < 8192; i += 256) {
    int n1 = i & 7, n0 = (i >> 3) & 3, r2 = (i >> 5) & 7, m1 = (i >> 8) & 7, m0 = i >> 11;
    float s = 0.f;
#pragma unroll
    for (int r1 = 0; r1 < 8; ++r1)
      s += c0[(m0 * 8 + r1) * 4 + n0] * c1[(m1 * 8 + r2) * 64 + r1 * 8 + n1];
    L[i] = s;
  }
  for (int i = t; i < 8192; i += 256) {
    int n3 = i & 3, n2 = (i >> 2) & 7, m3 = (i >> 5) & 3, m2 = (i >> 7) & 7, r2 = i >> 10;
    float s = 0.f;
#pragma unroll
    for (int r3 = 0; r3 < 8; ++r3)
      s += c2[(m2 * 8 + r3) * 64 + r2 * 8 + n2] * c3[m3 * 32 + r3 * 4 + n3];
    R[i] = s;
  }
  __syncthreads();
  int base = blockIdx.x * 4096;  // 4 rows of T per block, grid = 256
  for (int j = 0; j < 16; ++j) {
    int lin = j * 256 + t;
    int g = base + lin;
    int m = g >> 10, n = g & 1023;
    int m0 = m >> 8, m1 = (m >> 5) & 7, m2 = (m >> 2) & 7, m3 = m & 3;
    int n0 = n >> 8, n1 = (n >> 5) & 7, n2 = (n >> 2) & 7, n3 = n & 3;
    float s = 0.f;
#pragma unroll
    for (int r2 = 0; r2 < 8; ++r2)
      s += L[(((m0 * 8 + m1) * 8 + r2) * 4 + n0) * 8 + n1] *
           R[(((r2 * 8 + m2) * 4 + m3) * 8 + n2) * 4 + n3];
    Tb[(size_t)m * 1024 + n] = f2bf(s);
  }
}

// -------- kernel 2: depthwise 3x3 SAME conv with LDS strip staging ------
// block = (b, h-strip of 8, c-group of 32); LDS 10x32x32 f32 = 40KB.
// Kills the 9x L2/HBM re-read of the naive per-pixel version.
__global__ __launch_bounds__(256) void tt_conv3x3_lds(
    const float* __restrict__ x, const float* __restrict__ filt,
    unsigned short* __restrict__ D) {
  __shared__ float xs[10][32][32];
  int bid = blockIdx.x;                 // 2048 = 16b * 4strip * 32cg
  int cg = bid & 31, strip = (bid >> 5) & 3, b = bid >> 7;
  int h0 = strip * 8;
  int tid = threadIdx.x;
  float4 z4; z4.x = z4.y = z4.z = z4.w = 0.f;
#pragma unroll
  for (int i = 0; i < 10; ++i) {
    int j = tid + 256 * i;              // 2560 float4 chunks
    int row = j >> 8, w = (j >> 3) & 31, c4 = j & 7;
    int gh = h0 - 1 + row;
    float4 v = z4;
    if ((unsigned)gh < 32u)
      v = *reinterpret_cast<const float4*>(x + ((size_t)((b * 32 + gh) * 32 + w)) * 1024 + cg * 32 + c4 * 4);
    *reinterpret_cast<float4*>(&xs[row][w][c4 * 4]) = v;
  }
  float F[9];
#pragma unroll
  for (int i = 0; i < 9; ++i) F[i] = filt[i];
  __syncthreads();

  int c4 = tid & 7, w = tid >> 3;       // w in 0..31, c4 in 0..7
#define LD3(r, d0, d1, d2) { \
    d1 = *reinterpret_cast<const float4*>(&xs[r][w][c4 * 4]); \
    d0 = (w > 0)  ? *reinterpret_cast<const float4*>(&xs[r][w - 1][c4 * 4]) : z4; \
    d2 = (w < 31) ? *reinterpret_cast<const float4*>(&xs[r][w + 1][c4 * 4]) : z4; }
#define ACC4(a, f, v) { a.x += (f) * v.x; a.y += (f) * v.y; a.z += (f) * v.z; a.w += (f) * v.w; }
  float4 a00, a01, a02, a10, a11, a12, a20, a21, a22;
  LD3(0, a00, a01, a02);
  LD3(1, a10, a11, a12);
#pragma unroll
  for (int h = 0; h < 8; ++h) {
    LD3(h + 2, a20, a21, a22);
    float4 s = z4;
    ACC4(s, F[0], a00); ACC4(s, F[1], a01); ACC4(s, F[2], a02);
    ACC4(s, F[3], a10); ACC4(s, F[4], a11); ACC4(s, F[5], a12);
    ACC4(s, F[6], a20); ACC4(s, F[7], a21); ACC4(s, F[8], a22);
    ushort4 o;
    o.x = f2bf(s.x); o.y = f2bf(s.y); o.z = f2bf(s.z); o.w = f2bf(s.w);
    *reinterpret_cast<ushort4*>(&D[((size_t)(b * 1024 + (h0 + h) * 32 + w)) * 1024 + cg * 32 + c4 * 4]) = o;
    a00 = a10; a01 = a11; a02 = a12;
    a10 = a20; a11 = a21; a12 = a22;
  }
#undef LD3
#undef ACC4
}

// -------- kernel 3: 8-phase 256x256 GEMM, BK=64, 2-buffer LDS, counted vmcnt ----
// C[p,m] = relu( sum_k D[p,k]*Tb[m,k] + bias[m] ), M=16384, N=1024, K=1024.
__device__ inline void stage16(const unsigned short* g, unsigned short* l) {
  __builtin_amdgcn_global_load_lds(
      (const __attribute__((address_space(1))) void*)g,
      (__attribute__((address_space(3))) void*)l, 16, 0, 0);
}

__global__ __launch_bounds__(512, 2) void tt_gemm_8p(
    const unsigned short* __restrict__ A,   // [16384, 1024] bf16
    const unsigned short* __restrict__ Bt,  // [1024, 1024] bf16
    const float* __restrict__ bias,
    float* __restrict__ C) {
  __shared__ unsigned short lds[2][2][16384];  // [buf][A/B][256 rows x 64 k], 128 KiB
  const int tid = threadIdx.x;
  const int lane = tid & 63, wave = tid >> 6;
  const int wr = wave >> 2, wc = wave & 3;      // 2M x 4N waves, per-wave 128x64
  const int lr = lane & 15, kc = lane >> 4;

  // XCD-bijective swizzle (256 blocks, 8 XCDs)
  int lin = blockIdx.x + blockIdx.y * 64;
  int Lg = ((lin & 7) << 5) | (lin >> 3);
  int brow = (Lg & 63) * 256;
  int bcol = (Lg >> 6) * 256;

  // staging: 2048 16B-chunks per operand tile; thread stages 4 of each.
  // LDS linear chunk q = (row*8 + cp); holds source chunk c = cp ^ (row&7).
  int q8[4];
  const unsigned short* srcA[4];
  const unsigned short* srcB[4];
#pragma unroll
  for (int j = 0; j < 4; ++j) {
    int q = tid + 512 * j;
    int row = q >> 3, cp = q & 7, c = cp ^ (row & 7);
    q8[j] = q * 8;
    srcA[j] = A + (size_t)(brow + row) * 1024 + c * 8;
    srcB[j] = Bt + (size_t)(bcol + row) * 1024 + c * 8;
  }

  // swizzled ds_read offsets (in shorts)
  int offA[8][2], offB[4][2];
#pragma unroll
  for (int m = 0; m < 8; ++m) {
    int row = wr * 128 + m * 16 + lr;
#pragma unroll
    for (int ks = 0; ks < 2; ++ks) {
      int cp = (ks * 4 + kc) ^ (row & 7);
      offA[m][ks] = row * 64 + cp * 8;
    }
  }
#pragma unroll
  for (int n = 0; n < 4; ++n) {
    int row = wc * 64 + n * 16 + lr;
#pragma unroll
    for (int ks = 0; ks < 2; ++ks) {
      int cp = (ks * 4 + kc) ^ (row & 7);
      offB[n][ks] = row * 64 + cp * 8;
    }
  }

  f32x4 acc[8][4] = {};

#define SUBPHASE(RB, MH, KS, LOADB) { \
    short8 af[4]; \
    if (LOADB) { \
      _Pragma("unroll") for (int n = 0; n < 4; ++n) \
        bfr[n] = *reinterpret_cast<const short8*>(&lds[RB][1][offB[n][KS]]); \
    } \
    _Pragma("unroll") for (int m = 0; m < 4; ++m) \
      af[m] = *reinterpret_cast<const short8*>(&lds[RB][0][offA[(MH) * 4 + m][KS]]); \
    __builtin_amdgcn_s_barrier(); \
    asm volatile("s_waitcnt lgkmcnt(0)" ::: "memory"); \
    __builtin_amdgcn_sched_barrier(0); \
    __builtin_amdgcn_s_setprio(1); \
    _Pragma("unroll") for (int m = 0; m < 4; ++m) \
      _Pragma("unroll") for (int n = 0; n < 4; ++n) \
        acc[(MH) * 4 + m][n] = __builtin_amdgcn_mfma_f32_16x16x32_bf16(af[m], bfr[n], acc[(MH) * 4 + m][n], 0, 0, 0); \
    __builtin_amdgcn_s_setprio(0); \
    __builtin_amdgcn_sched_barrier(0); \
    __builtin_amdgcn_s_barrier(); \
  }

#define KITER(RB, SB, KT, DO_STAGE, VMS) { \
    if (DO_STAGE) { \
      _Pragma("unroll") for (int j = 0; j < 4; ++j) { \
        stage16(srcA[j] + (KT) * 64, &lds[SB][0][q8[j]]); \
        stage16(srcB[j] + (KT) * 64, &lds[SB][1][q8[j]]); \
      } \
    } \
    asm volatile("s_waitcnt vmcnt(" VMS ")" ::: "memory"); \
    __builtin_amdgcn_s_barrier(); \
    { short8 bfr[4]; \
      SUBPHASE(RB, 0, 0, 1) \
      SUBPHASE(RB, 1, 0, 0) \
      SUBPHASE(RB, 0, 1, 1) \
      SUBPHASE(RB, 1, 1, 0) } }

  // prologue: tile 0 into buf 0 (8 loads in flight)
#pragma unroll
  for (int j = 0; j < 4; ++j) {
    stage16(srcA[j], &lds[0][0][q8[j]]);
    stage16(srcB[j], &lds[0][1][q8[j]]);
  }

  for (int t = 0; t < 14; t += 2) {
    KITER(0, 1, t + 1, 1, "8")
    KITER(1, 0, t + 2, 1, "8")
  }
  KITER(0, 1, 15, 1, "8")   // tile 14, stage tile 15
  KITER(1, 0, 0, 0, "0")    // tile 15, epilogue drain

#undef KITER
#undef SUBPHASE

  // epilogue: bias + relu, fp32 store
#pragma unroll
  for (int n = 0; n < 4; ++n) {
    int col = bcol + wc * 64 + n * 16 + lr;
    float bv = bias[col];
#pragma unroll
    for (int m = 0; m < 8; ++m) {
#pragma unroll
      for (int j = 0; j < 4; ++j) {
        int row = brow + wr * 128 + m * 16 + kc * 4 + j;
        float v = acc[m][n][j] + bv;
        C[(size_t)row * 1024 + col] = v > 0.f ? v : 0.f;
      }
    }
  }
}

extern "C" void kernel_launch(void* const* d_in, const int* in_sizes, int n_in,
                              void* d_out, int out_size, void* d_ws, size_t ws_size,
                              hipStream_t stream) {
  const float* x = (const float*)d_in[0];
  const float* filt = (const float*)d_in[1];
  const float* c0 = (const float*)d_in[2];
  const float* c1 = (const float*)d_in[3];
  const float* c2 = (const float*)d_in[4];
  const float* c3 = (const float*)d_in[5];
  const float* bias = (const float*)d_in[6];
  float* out = (float*)d_out;

  unsigned short* Tb = (unsigned short*)d_ws;        // 2 MB
  unsigned short* D = Tb + (size_t)1024 * 1024;      // 32 MB

  tt_build_T<<<256, 256, 0, stream>>>(c0, c1, c2, c3, Tb);
  tt_conv3x3_lds<<<2048, 256, 0, stream>>>(x, filt, D);
  dim3 grid(64, 4);
  tt_gemm_8p<<<grid, 512, 0, stream>>>(D, Tb, bias, out);
}

// Round 4
// 79.881 us; speedup vs baseline: 1.4120x; 1.0317x over previous
//
#include <hip/hip_runtime.h>
#include <hip/hip_bf16.h>
#include <stdint.h>

typedef __attribute__((ext_vector_type(8))) short short8;
typedef __attribute__((ext_vector_type(4))) float f32x4;

__device__ inline unsigned short f2bf(float f) {
  union { float f; unsigned u; } v; v.f = f;
  unsigned r = v.u + 0x7fffu + ((v.u >> 16) & 1u);
  return (unsigned short)(r >> 16);
}

// -------- kernel 1: reconstruct T (1024x1024) as bf16, layout [m][n] ----
__global__ __launch_bounds__(256) void tt_build_T(
    const float* __restrict__ c0, const float* __restrict__ c1,
    const float* __restrict__ c2, const float* __restrict__ c3,
    unsigned short* __restrict__ Tb) {
  __shared__ float L[8192];
  __shared__ float R[8192];
  int t = threadIdx.x;
  for (int i = t; i < 8192; i += 256) {
    int n1 = i & 7, n0 = (i >> 3) & 3, r2 = (i >> 5) & 7, m1 = (i >> 8) & 7, m0 = i >> 11;
    float s = 0.f;
#pragma unroll
    for (int r1 = 0; r1 < 8; ++r1)
      s += c0[(m0 * 8 + r1) * 4 + n0] * c1[(m1 * 8 + r2) * 64 + r1 * 8 + n1];
    L[i] = s;
  }
  for (int i = t; i < 8192; i += 256) {
    int n3 = i & 3, n2 = (i >> 2) & 7, m3 = (i >> 5) & 3, m2 = (i >> 7) & 7, r2 = i >> 10;
    float s = 0.f;
#pragma unroll
    for (int r3 = 0; r3 < 8; ++r3)
      s += c2[(m2 * 8 + r3) * 64 + r2 * 8 + n2] * c3[m3 * 32 + r3 * 4 + n3];
    R[i] = s;
  }
  __syncthreads();
  int base = blockIdx.x * 4096;
  for (int j = 0; j < 16; ++j) {
    int lin = j * 256 + t;
    int g = base + lin;
    int m = g >> 10, n = g & 1023;
    int m0 = m >> 8, m1 = (m >> 5) & 7, m2 = (m >> 2) & 7, m3 = m & 3;
    int n0 = n >> 8, n1 = (n >> 5) & 7, n2 = (n >> 2) & 7, n3 = n & 3;
    float s = 0.f;
#pragma unroll
    for (int r2 = 0; r2 < 8; ++r2)
      s += L[(((m0 * 8 + m1) * 8 + r2) * 4 + n0) * 8 + n1] *
           R[(((r2 * 8 + m2) * 4 + m3) * 8 + n2) * 4 + n3];
    Tb[(size_t)m * 1024 + n] = f2bf(s);
  }
}

// -------- kernel 2: depthwise 3x3 SAME conv with LDS strip staging (at BW roofline) ----
__global__ __launch_bounds__(256) void tt_conv3x3_lds(
    const float* __restrict__ x, const float* __restrict__ filt,
    unsigned short* __restrict__ D) {
  __shared__ float xs[10][32][32];
  int bid = blockIdx.x;                 // 2048 = 16b * 4strip * 32cg
  int cg = bid & 31, strip = (bid >> 5) & 3, b = bid >> 7;
  int h0 = strip * 8;
  int tid = threadIdx.x;
  float4 z4; z4.x = z4.y = z4.z = z4.w = 0.f;
#pragma unroll
  for (int i = 0; i < 10; ++i) {
    int j = tid + 256 * i;
    int row = j >> 8, w = (j >> 3) & 31, c4 = j & 7;
    int gh = h0 - 1 + row;
    float4 v = z4;
    if ((unsigned)gh < 32u)
      v = *reinterpret_cast<const float4*>(x + ((size_t)((b * 32 + gh) * 32 + w)) * 1024 + cg * 32 + c4 * 4);
    *reinterpret_cast<float4*>(&xs[row][w][c4 * 4]) = v;
  }
  float F[9];
#pragma unroll
  for (int i = 0; i < 9; ++i) F[i] = filt[i];
  __syncthreads();

  int c4 = tid & 7, w = tid >> 3;
#define LD3(r, d0, d1, d2) { \
    d1 = *reinterpret_cast<const float4*>(&xs[r][w][c4 * 4]); \
    d0 = (w > 0)  ? *reinterpret_cast<const float4*>(&xs[r][w - 1][c4 * 4]) : z4; \
    d2 = (w < 31) ? *reinterpret_cast<const float4*>(&xs[r][w + 1][c4 * 4]) : z4; }
#define ACC4(a, f, v) { a.x += (f) * v.x; a.y += (f) * v.y; a.z += (f) * v.z; a.w += (f) * v.w; }
  float4 a00, a01, a02, a10, a11, a12, a20, a21, a22;
  LD3(0, a00, a01, a02);
  LD3(1, a10, a11, a12);
#pragma unroll
  for (int h = 0; h < 8; ++h) {
    LD3(h + 2, a20, a21, a22);
    float4 s = z4;
    ACC4(s, F[0], a00); ACC4(s, F[1], a01); ACC4(s, F[2], a02);
    ACC4(s, F[3], a10); ACC4(s, F[4], a11); ACC4(s, F[5], a12);
    ACC4(s, F[6], a20); ACC4(s, F[7], a21); ACC4(s, F[8], a22);
    ushort4 o;
    o.x = f2bf(s.x); o.y = f2bf(s.y); o.z = f2bf(s.z); o.w = f2bf(s.w);
    *reinterpret_cast<ushort4*>(&D[((size_t)(b * 1024 + (h0 + h) * 32 + w)) * 1024 + cg * 32 + c4 * 4]) = o;
    a00 = a10; a01 = a11; a02 = a12;
    a10 = a20; a11 = a21; a12 = a22;
  }
#undef LD3
#undef ACC4
}

// -------- kernel 3: 256x256 GEMM, BK=32, 3-buffer LDS ring, fine pipeline ----
// C[p,m] = relu( sum_k D[p,k]*Tb[m,k] + bias[m] ), M=16384, N=1024, K=1024.
// Swizzle: rows paired into 128B lines (8 x 16B slots); slot' = slot ^ (line&7).
// Staging pre-swizzles the GLOBAL source; LDS dest stays linear (gload_lds rule).
__device__ inline void stage16(const unsigned short* g, unsigned short* l) {
  __builtin_amdgcn_global_load_lds(
      (const __attribute__((address_space(1))) void*)g,
      (__attribute__((address_space(3))) void*)l, 16, 0, 0);
}

__global__ __launch_bounds__(512, 2) void tt_gemm_p3(
    const unsigned short* __restrict__ A,   // [16384, 1024] bf16
    const unsigned short* __restrict__ Bt,  // [1024, 1024] bf16
    const float* __restrict__ bias,
    float* __restrict__ C) {
  __shared__ unsigned short lds[3][2][8192];  // [ring][A/B][256 rows x 32 k], 96 KiB
  const int tid = threadIdx.x;
  const int lane = tid & 63, wave = tid >> 6;
  const int wr = wave >> 2, wc = wave & 3;      // 2M x 4N waves, per-wave 128x64
  const int lr = lane & 15, kc = lane >> 4;     // frag row lr, k-chunk kc
  const int rg = kc;                            // acc sub-col group

  // XCD-bijective swizzle (256 blocks, 8 XCDs)
  int lin = blockIdx.x + blockIdx.y * 64;
  int Lg = ((lin & 7) << 5) | (lin >> 3);
  int brow = (Lg & 63) * 256;
  int bcol = (Lg >> 6) * 256;

  // ---- staging descriptors: per op-tile 1024 chunks; thread stages q0=tid, q1=tid+512
  int rowq0, cq0, rowq1, cq1;
  { int q = tid;       int li = q >> 3, sp = q & 7, sl = sp ^ (li & 7); rowq0 = 2 * li + (sl >> 2); cq0 = sl & 3; }
  { int q = tid + 512; int li = q >> 3, sp = q & 7, sl = sp ^ (li & 7); rowq1 = 2 * li + (sl >> 2); cq1 = sl & 3; }
  const unsigned short* srcA0 = A + (size_t)(brow + rowq0) * 1024 + cq0 * 8;
  const unsigned short* srcA1 = A + (size_t)(brow + rowq1) * 1024 + cq1 * 8;
  const unsigned short* srcB0 = Bt + (size_t)(bcol + rowq0) * 1024 + cq0 * 8;
  const unsigned short* srcB1 = Bt + (size_t)(bcol + rowq1) * 1024 + cq1 * 8;
  const int l0 = tid * 8, l1 = (tid + 512) * 8;   // LDS short offsets (linear)

  // ---- swizzled ds_read offsets (shorts): fragment (row, kc)
  int offA[8], offB[4];
#pragma unroll
  for (int m = 0; m < 8; ++m) {
    int row = wr * 128 + m * 16 + lr;
    int li = row >> 1, sl = (row & 1) * 4 + kc;
    offA[m] = (li * 8 + (sl ^ (li & 7))) * 8;
  }
#pragma unroll
  for (int n = 0; n < 4; ++n) {
    int row = wc * 64 + n * 16 + lr;
    int li = row >> 1, sl = (row & 1) * 4 + kc;
    offB[n] = (li * 8 + (sl ^ (li & 7))) * 8;
  }

  f32x4 acc[8][4] = {};

#define STAGE_B(S, T) { stage16(srcB0 + (T) * 32, &lds[S][1][l0]); \
                        stage16(srcB1 + (T) * 32, &lds[S][1][l1]); }
#define STAGE_A(S, T) { stage16(srcA0 + (T) * 32, &lds[S][0][l0]); \
                        stage16(srcA1 + (T) * 32, &lds[S][0][l1]); }

  // KTILE: compute tile in buf RB; stage tile T2 into buf SB (if T2>=0); counted vmcnt.
#define KTILE(RB, SB, T2, VMS) { \
    short8 bfr[4]; \
    if ((T2) >= 0) STAGE_B(SB, T2); \
    asm volatile("s_waitcnt vmcnt(" VMS ")" ::: "memory"); \
    __builtin_amdgcn_s_barrier(); \
    { short8 af[4]; \
      _Pragma("unroll") for (int m = 0; m < 4; ++m) \
        af[m] = *reinterpret_cast<const short8*>(&lds[RB][0][offA[m]]); \
      _Pragma("unroll") for (int n = 0; n < 4; ++n) \
        bfr[n] = *reinterpret_cast<const short8*>(&lds[RB][1][offB[n]]); \
      asm volatile("s_waitcnt lgkmcnt(0)"); \
      __builtin_amdgcn_s_setprio(1); \
      _Pragma("unroll") for (int m = 0; m < 4; ++m) \
        _Pragma("unroll") for (int n = 0; n < 4; ++n) \
          acc[m][n] = __builtin_amdgcn_mfma_f32_16x16x32_bf16(bfr[n], af[m], acc[m][n], 0, 0, 0); \
      __builtin_amdgcn_s_setprio(0); } \
    __builtin_amdgcn_s_barrier(); \
    if ((T2) >= 0) STAGE_A(SB, T2); \
    __builtin_amdgcn_s_barrier(); \
    { short8 af[4]; \
      _Pragma("unroll") for (int m = 0; m < 4; ++m) \
        af[m] = *reinterpret_cast<const short8*>(&lds[RB][0][offA[4 + m]]); \
      asm volatile("s_waitcnt lgkmcnt(0)"); \
      __builtin_amdgcn_s_setprio(1); \
      _Pragma("unroll") for (int m = 0; m < 4; ++m) \
        _Pragma("unroll") for (int n = 0; n < 4; ++n) \
          acc[4 + m][n] = __builtin_amdgcn_mfma_f32_16x16x32_bf16(bfr[n], af[m], acc[4 + m][n], 0, 0, 0); \
      __builtin_amdgcn_s_setprio(0); } \
    __builtin_amdgcn_s_barrier(); }

  // prologue: tiles 0,1 fully staged (8 loads in flight)
  STAGE_B(0, 0); STAGE_A(0, 0);
  STAGE_B(1, 1); STAGE_A(1, 1);

  // main: tiles 0..29, stage t+2 (ring), vmcnt(6) = 1.5-tile depth
  for (int t = 0; t < 30; t += 3) {
    KTILE(0, 2, t + 2, "6")
    KTILE(1, 0, t + 3, "6")
    KTILE(2, 1, t + 4, "6")
  }
  KTILE(0, 0, -1, "4")   // tile 30
  KTILE(1, 1, -1, "0")   // tile 31

#undef KTILE
#undef STAGE_A
#undef STAGE_B

  // epilogue: bias + relu, f32x4 stores (acc j-dim is col-contiguous after operand swap)
#pragma unroll
  for (int n = 0; n < 4; ++n) {
    int col = bcol + wc * 64 + n * 16 + rg * 4;
    float4 bv = *reinterpret_cast<const float4*>(&bias[col]);
#pragma unroll
    for (int m = 0; m < 8; ++m) {
      int row = brow + wr * 128 + m * 16 + lr;
      f32x4 v = acc[m][n];
      float4 o;
      o.x = v[0] + bv.x; o.y = v[1] + bv.y; o.z = v[2] + bv.z; o.w = v[3] + bv.w;
      o.x = o.x > 0.f ? o.x : 0.f;
      o.y = o.y > 0.f ? o.y : 0.f;
      o.z = o.z > 0.f ? o.z : 0.f;
      o.w = o.w > 0.f ? o.w : 0.f;
      *reinterpret_cast<float4*>(&C[(size_t)row * 1024 + col]) = o;
    }
  }
}

extern "C" void kernel_launch(void* const* d_in, const int* in_sizes, int n_in,
                              void* d_out, int out_size, void* d_ws, size_t ws_size,
                              hipStream_t stream) {
  const float* x = (const float*)d_in[0];
  const float* filt = (const float*)d_in[1];
  const float* c0 = (const float*)d_in[2];
  const float* c1 = (const float*)d_in[3];
  const float* c2 = (const float*)d_in[4];
  const float* c3 = (const float*)d_in[5];
  const float* bias = (const float*)d_in[6];
  float* out = (float*)d_out;

  unsigned short* Tb = (unsigned short*)d_ws;        // 2 MB
  unsigned short* D = Tb + (size_t)1024 * 1024;      // 32 MB

  tt_build_T<<<256, 256, 0, stream>>>(c0, c1, c2, c3, Tb);
  tt_conv3x3_lds<<<2048, 256, 0, stream>>>(x, filt, D);
  dim3 grid(64, 4);
  tt_gemm_p3<<<grid, 512, 0, stream>>>(D, Tb, bias, out);
}